// Round 2
// baseline (5603.733 us; speedup 1.0000x reference)
//
#include <hip/hip_runtime.h>
#include <hip/hip_bf16.h>
#include <hip/hip_fp16.h>

typedef _Float16 f16;
typedef __attribute__((ext_vector_type(8))) _Float16 f16x8;
typedef __attribute__((ext_vector_type(4))) float f32x4;

__device__ __forceinline__ float sigmoidf_(float x) { return 1.0f / (1.0f + __expf(-x)); }

// in: R x C fp32 row-major -> out: C x R f16 row-major (i.e. transposed)
__global__ __launch_bounds__(256) void k_transpose_cvt(const float* __restrict__ in, f16* __restrict__ out, int R, int C) {
    int idx = blockIdx.x * 256 + threadIdx.x;
    if (idx < R * C) {
        int r = idx / C;
        int c = idx - r * C;
        out[(long)c * R + r] = (f16)in[idx];
    }
}

// ---------------- GEMM: C(MxN) = act(A(MxK) * BT(NxK)^T + bias) ----------------
// 128x128 block tile, BK=32, 4 waves each 64x64 (4x4 mfma 16x16x32 tiles)
// A_FP32: A is fp32 row-major, converted to f16 during LDS staging.

template <int DO_GELU, int A_FP32>
__global__ __launch_bounds__(256) void k_gemm_bt(
    const void* __restrict__ Av, const f16* __restrict__ BT, const float* __restrict__ bias,
    f16* __restrict__ C, int M, int N, int K)
{
    __shared__ f16 As[128 * 32];
    __shared__ f16 Bs[128 * 32];
    const int tid = threadIdx.x;
    const int lane = tid & 63;
    const int wave = tid >> 6;
    const long m0 = (long)blockIdx.x * 128;
    const long n0 = (long)blockIdx.y * 128;
    const int wm = (wave >> 1) * 64, wn = (wave & 1) * 64;
    const int l15 = lane & 15, lq = lane >> 4;

    f32x4 acc[4][4] = {};

    for (int k0 = 0; k0 < K; k0 += 32) {
        __syncthreads();
#pragma unroll
        for (int i = 0; i < 2; i++) {
            int v = tid + 256 * i;         // 512 vec8 chunks per tile
            int row = v >> 2, part = v & 3;
            if (A_FP32) {
                const float* A32 = (const float*)Av;
                const float* p = A32 + (m0 + row) * (long)K + k0 + part * 8;
                float4 v0 = *(const float4*)p;
                float4 v1 = *(const float4*)(p + 4);
                f16x8 o;
                o[0] = (f16)v0.x; o[1] = (f16)v0.y; o[2] = (f16)v0.z; o[3] = (f16)v0.w;
                o[4] = (f16)v1.x; o[5] = (f16)v1.y; o[6] = (f16)v1.z; o[7] = (f16)v1.w;
                *(f16x8*)&As[row * 32 + part * 8] = o;
            } else {
                const f16* A16 = (const f16*)Av;
                *(f16x8*)&As[row * 32 + part * 8] = *(const f16x8*)(A16 + (m0 + row) * (long)K + k0 + part * 8);
            }
            *(f16x8*)&Bs[row * 32 + part * 8] = *(const f16x8*)(BT + (n0 + row) * (long)K + k0 + part * 8);
        }
        __syncthreads();
        f16x8 af[4], bf[4];
#pragma unroll
        for (int i = 0; i < 4; i++) af[i] = *(const f16x8*)&As[(wm + i * 16 + l15) * 32 + lq * 8];
#pragma unroll
        for (int j = 0; j < 4; j++) bf[j] = *(const f16x8*)&Bs[(wn + j * 16 + l15) * 32 + lq * 8];
#pragma unroll
        for (int i = 0; i < 4; i++)
#pragma unroll
            for (int j = 0; j < 4; j++)
                acc[i][j] = __builtin_amdgcn_mfma_f32_16x16x32_f16(af[i], bf[j], acc[i][j], 0, 0, 0);
    }

#pragma unroll
    for (int i = 0; i < 4; i++) {
#pragma unroll
        for (int j = 0; j < 4; j++) {
#pragma unroll
            for (int r = 0; r < 4; r++) {
                long row = m0 + wm + i * 16 + lq * 4 + r;
                long col = n0 + wn + j * 16 + l15;
                float v = acc[i][j][r] + bias[col];
                if (DO_GELU) {
                    float u = 0.7978845608028654f * (v + 0.044715f * v * v * v);
                    v = 0.5f * v * (1.0f + tanhf(u));
                }
                C[row * (long)N + col] = (f16)v;
            }
        }
    }
}

// ---------------- LSTM step ----------------
// grid 256 blocks: blockIdx = bg*32 + hs ; bg: batch rows bg*32..+32 ; hs: hidden units hs*16..+16
// wave g (0..3) computes z-tile (32 x 16) for gate g via MFMA over K=512, then fused update.

__global__ __launch_bounds__(256) void k_lstm_step(
    const f16* __restrict__ WhT,      // 2048 x 512 (W_h transposed)
    const f16* __restrict__ gates_t,  // B x 2048 slice for this t (x-projection + bias)
    const f16* __restrict__ h_prev,   // B x 512 (ys slice t-1), unused if t==0
    f16* __restrict__ h_out,          // B x 512 (ys slice t)
    float* __restrict__ c_buf,        // B x 512 fp32
    int t)
{
    const int bg = blockIdx.x >> 5;
    const int hs = blockIdx.x & 31;
    const int B0 = bg * 32;
    const int j0 = hs * 16;
    const int tid = threadIdx.x;
    const int lane = tid & 63, wave = tid >> 6;
    const int l15 = lane & 15, lq = lane >> 4;

    __shared__ float zs[4][32][17];

    if (t > 0) {
        f32x4 acc0 = {0.f, 0.f, 0.f, 0.f}, acc1 = {0.f, 0.f, 0.f, 0.f};
        const f16* wp = WhT + ((long)(wave * 512 + j0 + l15)) * 512 + lq * 8;
        const f16* a0 = h_prev + ((long)(B0 + l15)) * 512 + lq * 8;
        const f16* a1 = a0 + 16 * 512;
#pragma unroll
        for (int k0 = 0; k0 < 512; k0 += 32) {
            f16x8 b = *(const f16x8*)(wp + k0);
            f16x8 x0 = *(const f16x8*)(a0 + k0);
            f16x8 x1 = *(const f16x8*)(a1 + k0);
            acc0 = __builtin_amdgcn_mfma_f32_16x16x32_f16(x0, b, acc0, 0, 0, 0);
            acc1 = __builtin_amdgcn_mfma_f32_16x16x32_f16(x1, b, acc1, 0, 0, 0);
        }
#pragma unroll
        for (int r = 0; r < 4; r++) {
            zs[wave][lq * 4 + r][l15] = acc0[r];
            zs[wave][16 + lq * 4 + r][l15] = acc1[r];
        }
    } else {
        for (int e = lane; e < 512; e += 64) zs[wave][e >> 4][e & 15] = 0.0f;
    }
    __syncthreads();

    for (int e = tid; e < 512; e += 256) {
        int row = e >> 4, j = e & 15;
        int grow = B0 + row, gj = j0 + j;
        const f16* gx = gates_t + (long)grow * 2048;
        float zi = zs[0][row][j] + (float)gx[0 * 512 + gj];
        float zf = zs[1][row][j] + (float)gx[1 * 512 + gj];
        float zg = zs[2][row][j] + (float)gx[2 * 512 + gj];
        float zo = zs[3][row][j] + (float)gx[3 * 512 + gj];
        float c = (t > 0) ? c_buf[(long)grow * 512 + gj] : 0.0f;
        c = sigmoidf_(zf) * c + sigmoidf_(zi) * tanhf(zg);
        float h = sigmoidf_(zo) * tanhf(c);
        c_buf[(long)grow * 512 + gj] = c;
        h_out[(long)grow * 512 + gj] = (f16)h;
    }
}

// ---------------- heads: mu, sigma, value ----------------
// block = 256 threads = 8 rows x 32 cols; grid = 131072/8 = 16384

__global__ __launch_bounds__(256) void k_heads(
    const f16* __restrict__ ys, const float* __restrict__ Wmu, const float* __restrict__ bmu,
    const float* __restrict__ logstd, const float* __restrict__ Wv, const float* __restrict__ bv,
    float* __restrict__ mu, float* __restrict__ sigma, float* __restrict__ value)
{
    __shared__ f16 hsm[8][512];
    const int tid = threadIdx.x;
    const long base_row = (long)blockIdx.x * 8;
    for (int v = tid; v < 512; v += 256) {   // 8 rows x 64 vec8 chunks
        int row = v >> 6, part = v & 63;
        *(f16x8*)&hsm[row][part * 8] = *(const f16x8*)(ys + (base_row + row) * 512 + part * 8);
    }
    __syncthreads();
    const int n = tid & 31, rl = tid >> 5;
    float accm = 0.0f, accv = 0.0f;
    for (int k = 0; k < 512; k++) accm += (float)hsm[rl][k] * Wmu[k * 32 + n];
    for (int kk = 0; kk < 16; kk++) {
        int k = n + kk * 32;
        accv += (float)hsm[rl][k] * Wv[k];
    }
    for (int off = 16; off; off >>= 1) accv += __shfl_down(accv, off, 32);
    long r = base_row + rl;
    mu[r * 32 + n] = accm + bmu[n];
    sigma[r * 32 + n] = expf(logstd[n]);
    if (n == 0) value[r] = accv + bv[0];
}

// ---------------- launcher ----------------
// ws layout (bytes):                                   size
//   ys          @ 0                                    134217728   (131072 x 512 f16)
//   gates_chunk @ 134217728                            67108864    (64*256 x 2048 f16)
//   feats_chunk @ 201326592                            16777216    (64*256 x 512 f16)
//   WencT       @ 218103808                            262144      (512 x 256 f16)
//   WiT         @ 218365952                            2097152     (2048 x 512 f16)
//   WhT         @ 220463104                            2097152     (2048 x 512 f16)
//   cbuf        @ 222560256                            524288      (256 x 512 f32)
//   total ~213 MB (round-1 crash attributed to 837 MB ws overrun)

extern "C" void kernel_launch(void* const* d_in, const int* in_sizes, int n_in,
                              void* d_out, int out_size, void* d_ws, size_t ws_size,
                              hipStream_t stream)
{
    const float* x      = (const float*)d_in[0];
    const float* W_enc  = (const float*)d_in[1];
    const float* b_enc  = (const float*)d_in[2];
    const float* W_i    = (const float*)d_in[3];
    const float* W_h    = (const float*)d_in[4];
    const float* b_lstm = (const float*)d_in[5];
    const float* W_mu   = (const float*)d_in[6];
    const float* b_mu   = (const float*)d_in[7];
    const float* log_std= (const float*)d_in[8];
    const float* W_v    = (const float*)d_in[9];
    const float* b_v    = (const float*)d_in[10];

    char* ws = (char*)d_ws;
    f16*   ys    = (f16*)(ws);
    f16*   gchunk= (f16*)(ws + 134217728);
    f16*   fchunk= (f16*)(ws + 201326592);
    f16*   WencT = (f16*)(ws + 218103808);
    f16*   WiT   = (f16*)(ws + 218365952);
    f16*   WhT   = (f16*)(ws + 220463104);
    float* cbuf  = (float*)(ws + 222560256);

    float* mu    = (float*)d_out;
    float* sigma = mu + 4194304;
    float* value = mu + 8388608;

    hipLaunchKernelGGL(k_transpose_cvt, dim3(512), dim3(256), 0, stream, W_enc, WencT, 256, 512);
    hipLaunchKernelGGL(k_transpose_cvt, dim3(4096), dim3(256), 0, stream, W_i, WiT, 512, 2048);
    hipLaunchKernelGGL(k_transpose_cvt, dim3(4096), dim3(256), 0, stream, W_h, WhT, 512, 2048);

    const int CH = 64;                       // timesteps per chunk
    for (int t0 = 0; t0 < 512; t0 += CH) {
        // feats_chunk = gelu(x[t0:t0+CH] @ W_enc + b_enc): M=16384, N=512, K=256 (A fp32)
        hipLaunchKernelGGL((k_gemm_bt<1, 1>), dim3(128, 4), dim3(256), 0, stream,
                           (const void*)(x + (long)t0 * 256 * 256), WencT, b_enc, fchunk,
                           16384, 512, 256);
        // gates_chunk = feats_chunk @ W_i + b_lstm: M=16384, N=2048, K=512
        hipLaunchKernelGGL((k_gemm_bt<0, 0>), dim3(128, 16), dim3(256), 0, stream,
                           (const void*)fchunk, WiT, b_lstm, gchunk,
                           16384, 2048, 512);
        for (int t = t0; t < t0 + CH; t++) {
            hipLaunchKernelGGL(k_lstm_step, dim3(256), dim3(256), 0, stream,
                               WhT, gchunk + (long)(t - t0) * 524288,
                               (t ? (const f16*)(ys + (long)(t - 1) * 131072) : (const f16*)nullptr),
                               ys + (long)t * 131072, cbuf, t);
        }
    }

    hipLaunchKernelGGL(k_heads, dim3(16384), dim3(256), 0, stream,
                       ys, W_mu, b_mu, log_std, W_v, b_v, mu, sigma, value);
}